// Round 9
// baseline (3113.075 us; speedup 1.0000x reference)
//
#include <hip/hip_runtime.h>

#define BB 16
#define LL 512
#define DD 128
#define CH 16
#define NCH (LL / CH)

// 8-lane all-reduce sum (lanes within a DPP half-row), pure VALU:
// quad xor1, quad xor2, then half-row mirror pairs the two quads.
__device__ __forceinline__ float red8(float v) {
    v += __int_as_float(__builtin_amdgcn_update_dpp(
            0, __float_as_int(v), 0xB1, 0xF, 0xF, true));
    v += __int_as_float(__builtin_amdgcn_update_dpp(
            0, __float_as_int(v), 0x4E, 0xF, 0xF, true));
    v += __int_as_float(__builtin_amdgcn_update_dpp(
            0, __float_as_int(v), 0x141, 0xF, 0xF, true));
    return v;
}

// Cap occupancy at 2 waves/EU (256-reg budget) AND suppress the allocator's
// default even arch/AGPR split — the 128-float loop-carried state must live in
// arch VGPRs or every touch pays v_accvgpr copies inside the dependent chains.
#if defined(__has_attribute)
#  if __has_attribute(amdgpu_agpr_alloc)
#    define SCAN_REGS __attribute__((amdgpu_waves_per_eu(2, 2), amdgpu_agpr_alloc(0)))
#  elif __has_attribute(amdgpu_no_agpr)
#    define SCAN_REGS __attribute__((amdgpu_waves_per_eu(2, 2), amdgpu_no_agpr))
#  else
#    define SCAN_REGS __attribute__((amdgpu_waves_per_eu(2, 2)))
#  endif
#else
#  define SCAN_REGS __attribute__((amdgpu_waves_per_eu(2, 2)))
#endif

// ---------------- transpose Wq, Wk, Wout (once per call, tiny) ----------------
__global__ void transpose3_kernel(const float* __restrict__ Wq,
                                  const float* __restrict__ Wk,
                                  const float* __restrict__ Wout,
                                  float* __restrict__ WqT,
                                  float* __restrict__ WkT,
                                  float* __restrict__ WoutT) {
    const float* src; float* dst;
    if (blockIdx.x == 0)      { src = Wq;   dst = WqT;   }
    else if (blockIdx.x == 1) { src = Wk;   dst = WkT;   }
    else                      { src = Wout; dst = WoutT; }
    for (int idx = threadIdx.x; idx < DD * DD; idx += blockDim.x) {
        int r = idx >> 7, c = idx & 127;
        dst[c * DD + r] = src[idx];
    }
}

// ---------------- prologue: q/k projections, k-normalize, P0 rotation, poly ----
__global__ __launch_bounds__(128) void prologue_kernel(
        const float* __restrict__ x, const float* __restrict__ WqT,
        const float* __restrict__ WkT, const float* __restrict__ P0,
        const float* __restrict__ log_gain, const float* __restrict__ coeffs,
        float* __restrict__ kphi, float* __restrict__ qphi) {
    const int row0 = blockIdx.x * 4;
    const int e = threadIdx.x;
    __shared__ float xs[4][DD];
    __shared__ float qrow[4][DD];
    __shared__ float wred[4][2];

    #pragma unroll
    for (int rr = 0; rr < 4; ++rr)
        xs[rr][e] = x[(size_t)(row0 + rr) * DD + e];
    __syncthreads();

    float aq[4] = {0,0,0,0}, ak[4] = {0,0,0,0};
    #pragma unroll 4
    for (int d = 0; d < DD; ++d) {
        float wq = WqT[d * DD + e];
        float wk = WkT[d * DD + e];
        #pragma unroll
        for (int rr = 0; rr < 4; ++rr) {
            float xv = xs[rr][d];
            aq[rr] = fmaf(xv, wq, aq[rr]);
            ak[rr] = fmaf(xv, wk, ak[rr]);
        }
    }
    const int lane = threadIdx.x & 63, wv = threadIdx.x >> 6;
    #pragma unroll
    for (int rr = 0; rr < 4; ++rr) {
        float s = ak[rr] * ak[rr];
        #pragma unroll
        for (int m = 1; m <= 32; m <<= 1) s += __shfl_xor(s, m);
        if (lane == 0) wred[rr][wv] = s;
    }
    __syncthreads();
    const float c0 = coeffs[0], c1v = coeffs[1];
    #pragma unroll
    for (int rr = 0; rr < 4; ++rr) {
        float s = wred[rr][0] + wred[rr][1];
        float kn = ak[rr] / fmaxf(sqrtf(s), 1e-12f);
        kphi[(size_t)(row0 + rr) * DD + e] = c0 * kn + c1v * kn * kn;
        qrow[rr][e] = aq[rr];
    }
    __syncthreads();
    float acc[4] = {0,0,0,0};
    #pragma unroll 4
    for (int d = 0; d < DD; ++d) {
        float pv = P0[d * DD + e];
        #pragma unroll
        for (int rr = 0; rr < 4; ++rr) acc[rr] = fmaf(qrow[rr][d], pv, acc[rr]);
    }
    const float g = expf(log_gain[e]);
    #pragma unroll
    for (int rr = 0; rr < 4; ++rr) {
        float qa = tanhf(g * acc[rr]);
        qphi[(size_t)(row0 + rr) * DD + e] = c0 * qa + c1v * qa * qa;
    }
}

// ---------------- main sequential scan: one block per batch --------------------
// 512 threads, chunked LDS staging (R8 structure: per-step barriers are
// vmem-free). NEW: chunk-stable values (kk = k cols, xv = x[r0], vc = k[r0])
// for step t+1 are prefetched into REGISTERS during phase 6 of step t — their
// LDS reads depend only on chunk staging, not the per-step barriers, so the
// post-barrier latency chains shrink. qq is issued in phase 4 right after the
// us/ps reads (LDS FIFO order: us/ps first) and arrives before phase 6.
// Thread (g = tid>>3, j = tid&7): rows {2g,2g+1}; interleaved column set
// col(m,l) = 4j + 32m + l -> conflict-free unpadded vector reads.
// A = S S^T S via exact rank-3 recurrence; ||S||_F^2 via scalar recurrence.
__global__ SCAN_REGS __launch_bounds__(512)
void scan_kernel(
        const float* __restrict__ kphi, const float* __restrict__ qphi,
        const float* __restrict__ x, const float* __restrict__ M0,
        const float* __restrict__ S0, float* __restrict__ ys) {
    const int b    = blockIdx.x;
    const int tid  = threadIdx.x;
    const int j    = tid & 7;
    const int g    = tid >> 3;
    const int r0   = 2 * g;
    const int w    = tid >> 6;
    const int lane = tid & 63;

    __shared__ __align__(16) float kc[2][CH * DD];
    __shared__ __align__(16) float qc[2][CH * DD];
    __shared__ __align__(16) float xc[2][CH * DD];
    __shared__ __align__(16) float yc[CH * DD];
    __shared__ __align__(16) float us[DD], ps[DD], wsv[DD], hs[DD];
    __shared__ float red[64];
    __shared__ float n2sh;

    float S[32], ST[32], A[32], M[32];
    {
        const float4* S04 = (const float4*)S0;
        const float4* M04 = (const float4*)M0;
        #pragma unroll
        for (int rl = 0; rl < 2; ++rl)
            #pragma unroll
            for (int m = 0; m < 4; ++m) {
                int f4 = (r0 + rl) * 32 + j + 8 * m;
                float4 s4 = S04[f4], m4 = M04[f4];
                int i = rl * 16 + 4 * m;
                S[i+0] = s4.x; S[i+1] = s4.y; S[i+2] = s4.z; S[i+3] = s4.w;
                M[i+0] = m4.x; M[i+1] = m4.y; M[i+2] = m4.z; M[i+3] = m4.w;
            }
        #pragma unroll
        for (int rl = 0; rl < 2; ++rl)
            #pragma unroll
            for (int m = 0; m < 4; ++m)
                #pragma unroll
                for (int l = 0; l < 4; ++l)
                    ST[rl*16 + 4*m + l] =
                        S0[(size_t)(4*j + 32*m + l) * DD + r0 + rl];
        #pragma unroll
        for (int i = 0; i < 32; ++i) A[i] = 0.f;   // exact when S0 == 0
    }

    // ||S0||^2 block reduction
    float sp = 0.f;
    #pragma unroll
    for (int i = 0; i < 32; ++i) sp = fmaf(S[i], S[i], sp);
    sp = red8(sp);
    if (j == 0) red[g] = sp;

    const size_t base = (size_t)b * LL * DD;

    // preload chunk 0 (each wave copies 3 x 1KB segments)
    #pragma unroll
    for (int i = 0; i < 3; ++i) {
        int seg = w * 3 + i, arr = seg >> 3, sub = seg & 7;
        const float* sp0 = (arr == 0 ? kphi : (arr == 1 ? qphi : x))
                           + base + sub * 256 + lane * 4;
        float* dp = (arr == 0 ? kc[0] : (arr == 1 ? qc[0] : xc[0]))
                    + sub * 256 + lane * 4;
        *(float4*)dp = *(const float4*)sp0;
    }
    __syncthreads();
    if (tid < 64) {
        float s = red[tid];
        #pragma unroll
        for (int m = 1; m <= 32; m <<= 1) s += __shfl_xor(s, m);
        if (tid == 0) n2sh = s;
    }

    // initial register prefetch for (tc=0, sl=0): chunk-stable LDS reads
    float kk[16];
    float2 xv2, vc2;
    {
        const float4* k4 = (const float4*)kc[0];
        #pragma unroll
        for (int m = 0; m < 4; ++m) {
            float4 v4 = k4[j + 8 * m];
            kk[4*m+0] = v4.x; kk[4*m+1] = v4.y;
            kk[4*m+2] = v4.z; kk[4*m+3] = v4.w;
        }
        xv2 = *(const float2*)&xc[0][r0];
        vc2 = *(const float2*)&kc[0][r0];
    }
    __syncthreads();
    float n2 = n2sh;

    const float a = 0.9f, a2v = 0.81f, a3v = 0.729f;

    #pragma unroll 1
    for (int tc = 0; tc < NCH; ++tc) {
        const int cb = tc & 1;
        const float* kcb = kc[cb];
        const float* qcb = qc[cb];
        const float* xcb = xc[cb];

        #pragma unroll 1
        for (int sl = 0; sl < CH; ++sl) {
            const int so = sl * DD;

            // issue next-chunk staging loads at chunk start (drained ~1x/chunk)
            float4 pre0, pre1, pre2;
            const bool doPre = (sl == 0) && (tc + 1 < NCH);
            if (doPre) {
                const size_t nbg = base + (size_t)(tc + 1) * CH * DD;
                {
                    int seg = w * 3 + 0, arr = seg >> 3, sub = seg & 7;
                    pre0 = *(const float4*)((arr == 0 ? kphi : (arr == 1 ? qphi : x))
                                            + nbg + sub * 256 + lane * 4);
                }
                {
                    int seg = w * 3 + 1, arr = seg >> 3, sub = seg & 7;
                    pre1 = *(const float4*)((arr == 0 ? kphi : (arr == 1 ? qphi : x))
                                            + nbg + sub * 256 + lane * 4);
                }
                {
                    int seg = w * 3 + 2, arr = seg >> 3, sub = seg & 7;
                    pre2 = *(const float4*)((arr == 0 ? kphi : (arr == 1 ? qphi : x))
                                            + nbg + sub * 256 + lane * 4);
                }
            }

            // ---- phase 2 (row side): pred = M k, p = S v, cv = v.v ----
            // kk / xv2 already in registers (prefetched last iteration)
            float pr0 = 0.f, pr1 = 0.f, pp0 = 0.f, pp1 = 0.f, cvp = 0.f;
            #pragma unroll
            for (int cl = 0; cl < 16; ++cl) {
                float kv = kk[cl];
                pr0 = fmaf(M[cl],      kv, pr0);
                pr1 = fmaf(M[16 + cl], kv, pr1);
                pp0 = fmaf(S[cl],      kv, pp0);
                pp1 = fmaf(S[16 + cl], kv, pp1);
                cvp = fmaf(kv, kv, cvp);
            }
            pr0 = red8(pr0); pr1 = red8(pr1);
            pp0 = red8(pp0); pp1 = red8(pp1);
            const float cv = red8(cvp);
            const float u0 = pr0 - xv2.x, u1 = pr1 - xv2.y;
            const float p0 = pp0, p1 = pp1;
            if (j == 0) {
                *(float2*)&us[r0] = make_float2(u0, u1);
                *(float2*)&ps[r0] = make_float2(p0, p1);
            }
            __syncthreads();                               // barrier 1 (LDS only)

            // ---- phase 4 (col side): w = S^T u, h = S^T p, dots; ST update ----
            float uu[16], pa[16], qq[16];
            {
                const float4* u4 = (const float4*)us;
                const float4* p4 = (const float4*)ps;
                #pragma unroll
                for (int m = 0; m < 4; ++m) {
                    float4 a4 = u4[j + 8 * m], b4 = p4[j + 8 * m];
                    uu[4*m+0] = a4.x; uu[4*m+1] = a4.y;
                    uu[4*m+2] = a4.z; uu[4*m+3] = a4.w;
                    pa[4*m+0] = b4.x; pa[4*m+1] = b4.y;
                    pa[4*m+2] = b4.z; pa[4*m+3] = b4.w;
                }
                // qq issued after us/ps (LDS FIFO): arrives during phase-4 compute
                const float4* q4 = (const float4*)(qcb + so);
                #pragma unroll
                for (int m = 0; m < 4; ++m) {
                    float4 c4v = q4[j + 8 * m];
                    qq[4*m+0] = c4v.x; qq[4*m+1] = c4v.y;
                    qq[4*m+2] = c4v.z; qq[4*m+3] = c4v.w;
                }
            }
            float w0 = 0.f, w1 = 0.f, h0 = 0.f, h1 = 0.f, cuup = 0.f, cupp = 0.f;
            #pragma unroll
            for (int cl = 0; cl < 16; ++cl) {
                float uv = uu[cl], pv = pa[cl];
                float st0 = ST[cl], st1 = ST[16 + cl];
                w0 = fmaf(st0, uv, w0);  w1 = fmaf(st1, uv, w1);
                h0 = fmaf(st0, pv, h0);  h1 = fmaf(st1, pv, h1);
                cuup = fmaf(uv, uv, cuup);
                cupp = fmaf(uv, pv, cupp);
                ST[cl]      = fmaf(a, st0, vc2.x * uv);    // old st used above only
                ST[16 + cl] = fmaf(a, st1, vc2.y * uv);
            }
            w0 = red8(w0); w1 = red8(w1); h0 = red8(h0); h1 = red8(h1);
            const float cu  = red8(cuup);
            const float cup = red8(cupp);
            n2 = a2v * n2 + 2.0f * a * cup + cu * cv;      // ||S_t||_F^2 recurrence
            if (j == 0) {
                *(float2*)&wsv[r0] = make_float2(w0, w1);
                *(float2*)&hs[r0]  = make_float2(h0, h1);
            }
            // commit next-chunk staging to the other LDS buffer
            if (doPre) {
                float* kn = kc[cb ^ 1]; float* qn = qc[cb ^ 1]; float* xn = xc[cb ^ 1];
                {
                    int seg = w * 3 + 0, arr = seg >> 3, sub = seg & 7;
                    *(float4*)((arr == 0 ? kn : (arr == 1 ? qn : xn))
                               + sub * 256 + lane * 4) = pre0;
                }
                {
                    int seg = w * 3 + 1, arr = seg >> 3, sub = seg & 7;
                    *(float4*)((arr == 0 ? kn : (arr == 1 ? qn : xn))
                               + sub * 256 + lane * 4) = pre1;
                }
                {
                    int seg = w * 3 + 2, arr = seg >> 3, sub = seg & 7;
                    *(float4*)((arr == 0 ? kn : (arr == 1 ? qn : xn))
                               + sub * 256 + lane * 4) = pre2;
                }
            }
            __syncthreads();                               // barrier 2 (LDS only*)

            // ---- phase 6 (row side): g = S w; rank-3 A; S, M updates; y = M q ----
            float ww[16], hh[16];
            {
                const float4* w4 = (const float4*)wsv;
                const float4* h4 = (const float4*)hs;
                #pragma unroll
                for (int m = 0; m < 4; ++m) {
                    float4 a4 = w4[j + 8 * m], b4 = h4[j + 8 * m];
                    ww[4*m+0] = a4.x;  ww[4*m+1] = a4.y;
                    ww[4*m+2] = a4.z;  ww[4*m+3] = a4.w;
                    hh[4*m+0] = b4.x;  hh[4*m+1] = b4.y;
                    hh[4*m+2] = b4.z;  hh[4*m+3] = b4.w;
                }
            }

            // prefetch chunk-stable values for the NEXT step (no barrier dep)
            float kkn[16]; float2 xvn, vcn;
            {
                int nsl = sl + 1;
                const float* ksrc = kcb;
                const float* xsrc = xcb;
                if (nsl == CH) {
                    nsl = 0;
                    if (tc + 1 < NCH) { ksrc = kc[cb ^ 1]; xsrc = xc[cb ^ 1]; }
                }
                const int nso = nsl * DD;
                const float4* k4 = (const float4*)(ksrc + nso);
                #pragma unroll
                for (int m = 0; m < 4; ++m) {
                    float4 v4 = k4[j + 8 * m];
                    kkn[4*m+0] = v4.x; kkn[4*m+1] = v4.y;
                    kkn[4*m+2] = v4.z; kkn[4*m+3] = v4.w;
                }
                xvn = *(const float2*)&xsrc[nso + r0];
                vcn = *(const float2*)&ksrc[nso + r0];
            }

            float g0 = 0.f, g1 = 0.f;
            #pragma unroll
            for (int cl = 0; cl < 16; ++cl) {
                g0 = fmaf(S[cl],      ww[cl], g0);
                g1 = fmaf(S[16 + cl], ww[cl], g1);
            }
            g0 = red8(g0); g1 = red8(g1);

            const float rho0 = a2v * g0 + a * cu * p0 + (a * cup + cv * cu) * u0;
            const float rho1 = a2v * g1 + a * cu * p1 + (a * cup + cv * cu) * u1;
            const float sg0  = a2v * p0 + a * cv * u0;
            const float sg1  = a2v * p1 + a * cv * u1;
            const float ta0  = a2v * u0, ta1 = a2v * u1;
            const float nrm  = sqrtf(fmaxf(n2, 0.f)) + 1e-6f;
            const float rn   = 1.0f / nrm;
            const float c1   = -0.015f * rn;    // 0.99M - 0.01*(1.5 S/n - 0.5 A/n^3)
            const float c2   = 0.005f * rn * rn * rn;

            float y0 = 0.f, y1 = 0.f;
            #pragma unroll
            for (int cl = 0; cl < 16; ++cl) {
                float kv = kk[cl], wv = ww[cl], hv = hh[cl], qv = qq[cl];
                S[cl]      = fmaf(a, S[cl],      u0 * kv);
                S[16 + cl] = fmaf(a, S[16 + cl], u1 * kv);
                A[cl]      = fmaf(a3v, A[cl],
                                  fmaf(rho0, kv, fmaf(sg0, wv, ta0 * hv)));
                A[16 + cl] = fmaf(a3v, A[16 + cl],
                                  fmaf(rho1, kv, fmaf(sg1, wv, ta1 * hv)));
                M[cl]      = fmaf(0.99f, M[cl],      fmaf(c1, S[cl],      c2 * A[cl]));
                M[16 + cl] = fmaf(0.99f, M[16 + cl], fmaf(c1, S[16 + cl], c2 * A[16 + cl]));
                y0 = fmaf(M[cl],      qv, y0);
                y1 = fmaf(M[16 + cl], qv, y1);
            }
            y0 = red8(y0); y1 = red8(y1);
            if (j == 0)
                *(float2*)&yc[so + r0] = make_float2(y0, y1);

            // rotate prefetched registers into place for the next step
            #pragma unroll
            for (int cl = 0; cl < 16; ++cl) kk[cl] = kkn[cl];
            xv2 = xvn; vc2 = vcn;
        }

        // chunk end: flush yc -> ys (one float4 per thread)
        __syncthreads();
        float4 yv = *(float4*)&yc[tid * 4];
        *(float4*)(ys + base + (size_t)tc * CH * DD + tid * 4) = yv;
    }
}

// ---------------- epilogue: out = ys @ Wout^T + bout ---------------------------
__global__ __launch_bounds__(128) void epilogue_kernel(
        const float* __restrict__ ys, const float* __restrict__ WoutT,
        const float* __restrict__ bout, float* __restrict__ out) {
    const int row0 = blockIdx.x * 4;
    const int e = threadIdx.x;
    __shared__ float yr[4][DD];
    #pragma unroll
    for (int rr = 0; rr < 4; ++rr)
        yr[rr][e] = ys[(size_t)(row0 + rr) * DD + e];
    __syncthreads();
    float acc[4] = {0,0,0,0};
    #pragma unroll 4
    for (int d = 0; d < DD; ++d) {
        float w = WoutT[d * DD + e];
        #pragma unroll
        for (int rr = 0; rr < 4; ++rr) acc[rr] = fmaf(yr[rr][d], w, acc[rr]);
    }
    const float bo = bout[e];
    #pragma unroll
    for (int rr = 0; rr < 4; ++rr)
        out[(size_t)(row0 + rr) * DD + e] = acc[rr] + bo;
}

extern "C" void kernel_launch(void* const* d_in, const int* in_sizes, int n_in,
                              void* d_out, int out_size, void* d_ws, size_t ws_size,
                              hipStream_t stream) {
    const float* x        = (const float*)d_in[0];
    const float* Wq       = (const float*)d_in[1];
    const float* Wk       = (const float*)d_in[2];
    const float* P0       = (const float*)d_in[3];
    const float* M0       = (const float*)d_in[4];
    const float* S0       = (const float*)d_in[5];
    const float* log_gain = (const float*)d_in[6];
    const float* coeffs   = (const float*)d_in[7];
    const float* Wout     = (const float*)d_in[8];
    const float* bout     = (const float*)d_in[9];
    float* out = (float*)d_out;

    float* ws    = (float*)d_ws;
    float* WqT   = ws;                      // 16384
    float* WkT   = ws + 16384;              // 16384
    float* WoutT = ws + 32768;              // 16384
    float* kphi  = ws + 49152;              // B*L*D each below
    float* qphi  = kphi + (size_t)BB * LL * DD;
    float* ysb   = qphi + (size_t)BB * LL * DD;

    hipLaunchKernelGGL(transpose3_kernel, dim3(3), dim3(256), 0, stream,
                       Wq, Wk, Wout, WqT, WkT, WoutT);
    hipLaunchKernelGGL(prologue_kernel, dim3(BB * LL / 4), dim3(128), 0, stream,
                       x, WqT, WkT, P0, log_gain, coeffs, kphi, qphi);
    hipLaunchKernelGGL(scan_kernel, dim3(BB), dim3(512), 0, stream,
                       kphi, qphi, x, M0, S0, ysb);
    hipLaunchKernelGGL(epilogue_kernel, dim3(BB * LL / 4), dim3(128), 0, stream,
                       ysb, WoutT, bout, out);
}

// Round 10
// 2401.736 us; speedup vs baseline: 1.2962x; 1.2962x over previous
//
#include <hip/hip_runtime.h>

#define BB 16
#define LL 512
#define DD 128
#define CH 16
#define NCH (LL / CH)

// 8-lane all-reduce sum (lanes within a DPP half-row), pure VALU:
// quad xor1, quad xor2, then half-row mirror pairs the two quads.
__device__ __forceinline__ float red8(float v) {
    v += __int_as_float(__builtin_amdgcn_update_dpp(
            0, __float_as_int(v), 0xB1, 0xF, 0xF, true));
    v += __int_as_float(__builtin_amdgcn_update_dpp(
            0, __float_as_int(v), 0x4E, 0xF, 0xF, true));
    v += __int_as_float(__builtin_amdgcn_update_dpp(
            0, __float_as_int(v), 0x141, 0xF, 0xF, true));
    return v;
}

// Cap at 2 waves/EU (one 8-wave block per CU resident anyway; grid = 16).
#define SCAN_REGS __attribute__((amdgpu_waves_per_eu(2, 2)))

// ---------------- transpose Wq, Wk, Wout (once per call, tiny) ----------------
__global__ void transpose3_kernel(const float* __restrict__ Wq,
                                  const float* __restrict__ Wk,
                                  const float* __restrict__ Wout,
                                  float* __restrict__ WqT,
                                  float* __restrict__ WkT,
                                  float* __restrict__ WoutT) {
    const float* src; float* dst;
    if (blockIdx.x == 0)      { src = Wq;   dst = WqT;   }
    else if (blockIdx.x == 1) { src = Wk;   dst = WkT;   }
    else                      { src = Wout; dst = WoutT; }
    for (int idx = threadIdx.x; idx < DD * DD; idx += blockDim.x) {
        int r = idx >> 7, c = idx & 127;
        dst[c * DD + r] = src[idx];
    }
}

// ---------------- prologue: q/k projections, k-normalize, P0 rotation, poly ----
__global__ __launch_bounds__(128) void prologue_kernel(
        const float* __restrict__ x, const float* __restrict__ WqT,
        const float* __restrict__ WkT, const float* __restrict__ P0,
        const float* __restrict__ log_gain, const float* __restrict__ coeffs,
        float* __restrict__ kphi, float* __restrict__ qphi) {
    const int row0 = blockIdx.x * 4;
    const int e = threadIdx.x;
    __shared__ float xs[4][DD];
    __shared__ float qrow[4][DD];
    __shared__ float wred[4][2];

    #pragma unroll
    for (int rr = 0; rr < 4; ++rr)
        xs[rr][e] = x[(size_t)(row0 + rr) * DD + e];
    __syncthreads();

    float aq[4] = {0,0,0,0}, ak[4] = {0,0,0,0};
    #pragma unroll 4
    for (int d = 0; d < DD; ++d) {
        float wq = WqT[d * DD + e];
        float wk = WkT[d * DD + e];
        #pragma unroll
        for (int rr = 0; rr < 4; ++rr) {
            float xv = xs[rr][d];
            aq[rr] = fmaf(xv, wq, aq[rr]);
            ak[rr] = fmaf(xv, wk, ak[rr]);
        }
    }
    const int lane = threadIdx.x & 63, wv = threadIdx.x >> 6;
    #pragma unroll
    for (int rr = 0; rr < 4; ++rr) {
        float s = ak[rr] * ak[rr];
        #pragma unroll
        for (int m = 1; m <= 32; m <<= 1) s += __shfl_xor(s, m);
        if (lane == 0) wred[rr][wv] = s;
    }
    __syncthreads();
    const float c0 = coeffs[0], c1v = coeffs[1];
    #pragma unroll
    for (int rr = 0; rr < 4; ++rr) {
        float s = wred[rr][0] + wred[rr][1];
        float kn = ak[rr] / fmaxf(sqrtf(s), 1e-12f);
        kphi[(size_t)(row0 + rr) * DD + e] = c0 * kn + c1v * kn * kn;
        qrow[rr][e] = aq[rr];
    }
    __syncthreads();
    float acc[4] = {0,0,0,0};
    #pragma unroll 4
    for (int d = 0; d < DD; ++d) {
        float pv = P0[d * DD + e];
        #pragma unroll
        for (int rr = 0; rr < 4; ++rr) acc[rr] = fmaf(qrow[rr][d], pv, acc[rr]);
    }
    const float g = expf(log_gain[e]);
    #pragma unroll
    for (int rr = 0; rr < 4; ++rr) {
        float qa = tanhf(g * acc[rr]);
        qphi[(size_t)(row0 + rr) * DD + e] = c0 * qa + c1v * qa * qa;
    }
}

// ---------------- main sequential scan: one block per batch --------------------
// R8 structure (chunked LDS staging, vmem-free per-step barriers) with two
// pressure-neutral critical-path cuts:
//  (1) every reduction uses 2-way split accumulators (dep chain 16->8 fmaf);
//  (2) qq is read in phase 4 (chunk-stable) so it lands before phase 6.
// R9's register rotation (kkn/xvn/vcn) is REVERTED — it raised peak liveness
// past the 128-arch-VGPR allocation and regressed 1918->2990 us.
// Thread (g = tid>>3, j = tid&7): rows {2g,2g+1}; interleaved column set
// col(m,l) = 4j + 32m + l -> conflict-free unpadded vector reads.
// A = S S^T S via exact rank-3 recurrence; ||S||_F^2 via scalar recurrence.
__global__ SCAN_REGS __launch_bounds__(512)
void scan_kernel(
        const float* __restrict__ kphi, const float* __restrict__ qphi,
        const float* __restrict__ x, const float* __restrict__ M0,
        const float* __restrict__ S0, float* __restrict__ ys) {
    const int b    = blockIdx.x;
    const int tid  = threadIdx.x;
    const int j    = tid & 7;
    const int g    = tid >> 3;
    const int r0   = 2 * g;
    const int w    = tid >> 6;
    const int lane = tid & 63;

    __shared__ __align__(16) float kc[2][CH * DD];
    __shared__ __align__(16) float qc[2][CH * DD];
    __shared__ __align__(16) float xc[2][CH * DD];
    __shared__ __align__(16) float yc[CH * DD];
    __shared__ __align__(16) float us[DD], ps[DD], wsv[DD], hs[DD];
    __shared__ float red[64];
    __shared__ float n2sh;

    float S[32], ST[32], A[32], M[32];
    {
        const float4* S04 = (const float4*)S0;
        const float4* M04 = (const float4*)M0;
        #pragma unroll
        for (int rl = 0; rl < 2; ++rl)
            #pragma unroll
            for (int m = 0; m < 4; ++m) {
                int f4 = (r0 + rl) * 32 + j + 8 * m;
                float4 s4 = S04[f4], m4 = M04[f4];
                int i = rl * 16 + 4 * m;
                S[i+0] = s4.x; S[i+1] = s4.y; S[i+2] = s4.z; S[i+3] = s4.w;
                M[i+0] = m4.x; M[i+1] = m4.y; M[i+2] = m4.z; M[i+3] = m4.w;
            }
        #pragma unroll
        for (int rl = 0; rl < 2; ++rl)
            #pragma unroll
            for (int m = 0; m < 4; ++m)
                #pragma unroll
                for (int l = 0; l < 4; ++l)
                    ST[rl*16 + 4*m + l] =
                        S0[(size_t)(4*j + 32*m + l) * DD + r0 + rl];
        #pragma unroll
        for (int i = 0; i < 32; ++i) A[i] = 0.f;   // exact when S0 == 0
    }

    // ||S0||^2 block reduction
    float sp = 0.f;
    #pragma unroll
    for (int i = 0; i < 32; ++i) sp = fmaf(S[i], S[i], sp);
    sp = red8(sp);
    if (j == 0) red[g] = sp;

    const size_t base = (size_t)b * LL * DD;

    // preload chunk 0 (each wave copies 3 x 1KB segments)
    #pragma unroll
    for (int i = 0; i < 3; ++i) {
        int seg = w * 3 + i, arr = seg >> 3, sub = seg & 7;
        const float* sp0 = (arr == 0 ? kphi : (arr == 1 ? qphi : x))
                           + base + sub * 256 + lane * 4;
        float* dp = (arr == 0 ? kc[0] : (arr == 1 ? qc[0] : xc[0]))
                    + sub * 256 + lane * 4;
        *(float4*)dp = *(const float4*)sp0;
    }
    __syncthreads();
    if (tid < 64) {
        float s = red[tid];
        #pragma unroll
        for (int m = 1; m <= 32; m <<= 1) s += __shfl_xor(s, m);
        if (tid == 0) n2sh = s;
    }
    __syncthreads();
    float n2 = n2sh;

    const float a = 0.9f, a2v = 0.81f, a3v = 0.729f;

    #pragma unroll 1
    for (int tc = 0; tc < NCH; ++tc) {
        const int cb = tc & 1;
        const float* kcb = kc[cb];
        const float* qcb = qc[cb];
        const float* xcb = xc[cb];

        #pragma unroll 1
        for (int sl = 0; sl < CH; ++sl) {
            const int so = sl * DD;

            // issue next-chunk staging loads at chunk start (drained ~1x/chunk)
            float4 pre0, pre1, pre2;
            const bool doPre = (sl == 0) && (tc + 1 < NCH);
            if (doPre) {
                const size_t nbg = base + (size_t)(tc + 1) * CH * DD;
                {
                    int seg = w * 3 + 0, arr = seg >> 3, sub = seg & 7;
                    pre0 = *(const float4*)((arr == 0 ? kphi : (arr == 1 ? qphi : x))
                                            + nbg + sub * 256 + lane * 4);
                }
                {
                    int seg = w * 3 + 1, arr = seg >> 3, sub = seg & 7;
                    pre1 = *(const float4*)((arr == 0 ? kphi : (arr == 1 ? qphi : x))
                                            + nbg + sub * 256 + lane * 4);
                }
                {
                    int seg = w * 3 + 2, arr = seg >> 3, sub = seg & 7;
                    pre2 = *(const float4*)((arr == 0 ? kphi : (arr == 1 ? qphi : x))
                                            + nbg + sub * 256 + lane * 4);
                }
            }

            // ---- phase 2 (row side): pred = M k, p = S v, cv = v.v ----
            float kk[16];
            {
                const float4* k4 = (const float4*)(kcb + so);
                #pragma unroll
                for (int m = 0; m < 4; ++m) {
                    float4 v4 = k4[j + 8 * m];
                    kk[4*m+0] = v4.x; kk[4*m+1] = v4.y;
                    kk[4*m+2] = v4.z; kk[4*m+3] = v4.w;
                }
            }
            float pr0a = 0.f, pr0b = 0.f, pr1a = 0.f, pr1b = 0.f;
            float pp0a = 0.f, pp0b = 0.f, pp1a = 0.f, pp1b = 0.f;
            float cva = 0.f, cvb = 0.f;
            #pragma unroll
            for (int cl = 0; cl < 8; ++cl) {
                float kvA = kk[cl], kvB = kk[8 + cl];
                pr0a = fmaf(M[cl],      kvA, pr0a);
                pr0b = fmaf(M[8 + cl],  kvB, pr0b);
                pr1a = fmaf(M[16 + cl], kvA, pr1a);
                pr1b = fmaf(M[24 + cl], kvB, pr1b);
                pp0a = fmaf(S[cl],      kvA, pp0a);
                pp0b = fmaf(S[8 + cl],  kvB, pp0b);
                pp1a = fmaf(S[16 + cl], kvA, pp1a);
                pp1b = fmaf(S[24 + cl], kvB, pp1b);
                cva  = fmaf(kvA, kvA, cva);
                cvb  = fmaf(kvB, kvB, cvb);
            }
            float pr0 = red8(pr0a + pr0b);
            float pr1 = red8(pr1a + pr1b);
            float pp0 = red8(pp0a + pp0b);
            float pp1 = red8(pp1a + pp1b);
            const float cv = red8(cva + cvb);
            const float2 xv = *(const float2*)&xcb[so + r0];
            const float u0 = pr0 - xv.x, u1 = pr1 - xv.y;
            const float p0 = pp0, p1 = pp1;
            if (j == 0) {
                *(float2*)&us[r0] = make_float2(u0, u1);
                *(float2*)&ps[r0] = make_float2(p0, p1);
            }
            __syncthreads();                               // barrier 1 (LDS only)

            // ---- phase 4 (col side): w = S^T u, h = S^T p, dots; ST update ----
            float uu[16], pa[16], qq[16];
            {
                const float4* u4 = (const float4*)us;
                const float4* p4 = (const float4*)ps;
                #pragma unroll
                for (int m = 0; m < 4; ++m) {
                    float4 a4 = u4[j + 8 * m], b4 = p4[j + 8 * m];
                    uu[4*m+0] = a4.x; uu[4*m+1] = a4.y;
                    uu[4*m+2] = a4.z; uu[4*m+3] = a4.w;
                    pa[4*m+0] = b4.x; pa[4*m+1] = b4.y;
                    pa[4*m+2] = b4.z; pa[4*m+3] = b4.w;
                }
                // qq issued after us/ps (chunk-stable): lands before phase 6
                const float4* q4 = (const float4*)(qcb + so);
                #pragma unroll
                for (int m = 0; m < 4; ++m) {
                    float4 c4v = q4[j + 8 * m];
                    qq[4*m+0] = c4v.x; qq[4*m+1] = c4v.y;
                    qq[4*m+2] = c4v.z; qq[4*m+3] = c4v.w;
                }
            }
            const float2 vc = *(const float2*)&kcb[so + r0];
            float w0a = 0.f, w0b = 0.f, w1a = 0.f, w1b = 0.f;
            float h0a = 0.f, h0b = 0.f, h1a = 0.f, h1b = 0.f;
            float cua = 0.f, cub = 0.f, cpa = 0.f, cpb = 0.f;
            #pragma unroll
            for (int cl = 0; cl < 8; ++cl) {
                float uvA = uu[cl], uvB = uu[8 + cl];
                float pvA = pa[cl], pvB = pa[8 + cl];
                float st0A = ST[cl],      st0B = ST[8 + cl];
                float st1A = ST[16 + cl], st1B = ST[24 + cl];
                w0a = fmaf(st0A, uvA, w0a);  w0b = fmaf(st0B, uvB, w0b);
                w1a = fmaf(st1A, uvA, w1a);  w1b = fmaf(st1B, uvB, w1b);
                h0a = fmaf(st0A, pvA, h0a);  h0b = fmaf(st0B, pvB, h0b);
                h1a = fmaf(st1A, pvA, h1a);  h1b = fmaf(st1B, pvB, h1b);
                cua = fmaf(uvA, uvA, cua);   cub = fmaf(uvB, uvB, cub);
                cpa = fmaf(uvA, pvA, cpa);   cpb = fmaf(uvB, pvB, cpb);
                ST[cl]      = fmaf(a, st0A, vc.x * uvA);   // old st used above only
                ST[8 + cl]  = fmaf(a, st0B, vc.x * uvB);
                ST[16 + cl] = fmaf(a, st1A, vc.y * uvA);
                ST[24 + cl] = fmaf(a, st1B, vc.y * uvB);
            }
            float w0 = red8(w0a + w0b);
            float w1 = red8(w1a + w1b);
            float h0 = red8(h0a + h0b);
            float h1 = red8(h1a + h1b);
            const float cu  = red8(cua + cub);
            const float cup = red8(cpa + cpb);
            n2 = a2v * n2 + 2.0f * a * cup + cu * cv;      // ||S_t||_F^2 recurrence
            if (j == 0) {
                *(float2*)&wsv[r0] = make_float2(w0, w1);
                *(float2*)&hs[r0]  = make_float2(h0, h1);
            }
            // commit next-chunk staging to the other LDS buffer
            if (doPre) {
                float* kn = kc[cb ^ 1]; float* qn = qc[cb ^ 1]; float* xn = xc[cb ^ 1];
                {
                    int seg = w * 3 + 0, arr = seg >> 3, sub = seg & 7;
                    *(float4*)((arr == 0 ? kn : (arr == 1 ? qn : xn))
                               + sub * 256 + lane * 4) = pre0;
                }
                {
                    int seg = w * 3 + 1, arr = seg >> 3, sub = seg & 7;
                    *(float4*)((arr == 0 ? kn : (arr == 1 ? qn : xn))
                               + sub * 256 + lane * 4) = pre1;
                }
                {
                    int seg = w * 3 + 2, arr = seg >> 3, sub = seg & 7;
                    *(float4*)((arr == 0 ? kn : (arr == 1 ? qn : xn))
                               + sub * 256 + lane * 4) = pre2;
                }
            }
            __syncthreads();                               // barrier 2 (LDS only*)

            // ---- phase 6 (row side): g = S w; rank-3 A; S, M updates; y = M q ----
            float ww[16], hh[16];
            {
                const float4* w4 = (const float4*)wsv;
                const float4* h4 = (const float4*)hs;
                #pragma unroll
                for (int m = 0; m < 4; ++m) {
                    float4 a4 = w4[j + 8 * m], b4 = h4[j + 8 * m];
                    ww[4*m+0] = a4.x;  ww[4*m+1] = a4.y;
                    ww[4*m+2] = a4.z;  ww[4*m+3] = a4.w;
                    hh[4*m+0] = b4.x;  hh[4*m+1] = b4.y;
                    hh[4*m+2] = b4.z;  hh[4*m+3] = b4.w;
                }
            }
            float g0a = 0.f, g0b = 0.f, g1a = 0.f, g1b = 0.f;
            #pragma unroll
            for (int cl = 0; cl < 8; ++cl) {
                float wvA = ww[cl], wvB = ww[8 + cl];
                g0a = fmaf(S[cl],      wvA, g0a);
                g0b = fmaf(S[8 + cl],  wvB, g0b);
                g1a = fmaf(S[16 + cl], wvA, g1a);
                g1b = fmaf(S[24 + cl], wvB, g1b);
            }
            float g0 = red8(g0a + g0b);
            float g1 = red8(g1a + g1b);

            const float rho0 = a2v * g0 + a * cu * p0 + (a * cup + cv * cu) * u0;
            const float rho1 = a2v * g1 + a * cu * p1 + (a * cup + cv * cu) * u1;
            const float sg0  = a2v * p0 + a * cv * u0;
            const float sg1  = a2v * p1 + a * cv * u1;
            const float ta0  = a2v * u0, ta1 = a2v * u1;
            const float nrm  = sqrtf(fmaxf(n2, 0.f)) + 1e-6f;
            const float rn   = 1.0f / nrm;
            const float c1   = -0.015f * rn;    // 0.99M - 0.01*(1.5 S/n - 0.5 A/n^3)
            const float c2   = 0.005f * rn * rn * rn;

            float y0a = 0.f, y0b = 0.f, y1a = 0.f, y1b = 0.f;
            #pragma unroll
            for (int cl = 0; cl < 8; ++cl) {
                #pragma unroll
                for (int hf = 0; hf < 2; ++hf) {
                    int i = cl + 8 * hf;
                    float kv = kk[i], wv = ww[i], hv = hh[i], qv = qq[i];
                    S[i]      = fmaf(a, S[i],      u0 * kv);
                    S[16 + i] = fmaf(a, S[16 + i], u1 * kv);
                    A[i]      = fmaf(a3v, A[i],
                                     fmaf(rho0, kv, fmaf(sg0, wv, ta0 * hv)));
                    A[16 + i] = fmaf(a3v, A[16 + i],
                                     fmaf(rho1, kv, fmaf(sg1, wv, ta1 * hv)));
                    M[i]      = fmaf(0.99f, M[i],      fmaf(c1, S[i],      c2 * A[i]));
                    M[16 + i] = fmaf(0.99f, M[16 + i], fmaf(c1, S[16 + i], c2 * A[16 + i]));
                    if (hf == 0) {
                        y0a = fmaf(M[i],      qv, y0a);
                        y1a = fmaf(M[16 + i], qv, y1a);
                    } else {
                        y0b = fmaf(M[i],      qv, y0b);
                        y1b = fmaf(M[16 + i], qv, y1b);
                    }
                }
            }
            float y0 = red8(y0a + y0b);
            float y1 = red8(y1a + y1b);
            if (j == 0)
                *(float2*)&yc[so + r0] = make_float2(y0, y1);
        }

        // chunk end: flush yc -> ys (one float4 per thread)
        __syncthreads();
        float4 yv = *(float4*)&yc[tid * 4];
        *(float4*)(ys + base + (size_t)tc * CH * DD + tid * 4) = yv;
    }
}

// ---------------- epilogue: out = ys @ Wout^T + bout ---------------------------
__global__ __launch_bounds__(128) void epilogue_kernel(
        const float* __restrict__ ys, const float* __restrict__ WoutT,
        const float* __restrict__ bout, float* __restrict__ out) {
    const int row0 = blockIdx.x * 4;
    const int e = threadIdx.x;
    __shared__ float yr[4][DD];
    #pragma unroll
    for (int rr = 0; rr < 4; ++rr)
        yr[rr][e] = ys[(size_t)(row0 + rr) * DD + e];
    __syncthreads();
    float acc[4] = {0,0,0,0};
    #pragma unroll 4
    for (int d = 0; d < DD; ++d) {
        float w = WoutT[d * DD + e];
        #pragma unroll
        for (int rr = 0; rr < 4; ++rr) acc[rr] = fmaf(yr[rr][d], w, acc[rr]);
    }
    const float bo = bout[e];
    #pragma unroll
    for (int rr = 0; rr < 4; ++rr)
        out[(size_t)(row0 + rr) * DD + e] = acc[rr] + bo;
}

extern "C" void kernel_launch(void* const* d_in, const int* in_sizes, int n_in,
                              void* d_out, int out_size, void* d_ws, size_t ws_size,
                              hipStream_t stream) {
    const float* x        = (const float*)d_in[0];
    const float* Wq       = (const float*)d_in[1];
    const float* Wk       = (const float*)d_in[2];
    const float* P0       = (const float*)d_in[3];
    const float* M0       = (const float*)d_in[4];
    const float* S0       = (const float*)d_in[5];
    const float* log_gain = (const float*)d_in[6];
    const float* coeffs   = (const float*)d_in[7];
    const float* Wout     = (const float*)d_in[8];
    const float* bout     = (const float*)d_in[9];
    float* out = (float*)d_out;

    float* ws    = (float*)d_ws;
    float* WqT   = ws;                      // 16384
    float* WkT   = ws + 16384;              // 16384
    float* WoutT = ws + 32768;              // 16384
    float* kphi  = ws + 49152;              // B*L*D each below
    float* qphi  = kphi + (size_t)BB * LL * DD;
    float* ysb   = qphi + (size_t)BB * LL * DD;

    hipLaunchKernelGGL(transpose3_kernel, dim3(3), dim3(256), 0, stream,
                       Wq, Wk, Wout, WqT, WkT, WoutT);
    hipLaunchKernelGGL(prologue_kernel, dim3(BB * LL / 4), dim3(128), 0, stream,
                       x, WqT, WkT, P0, log_gain, coeffs, kphi, qphi);
    hipLaunchKernelGGL(scan_kernel, dim3(BB), dim3(512), 0, stream,
                       kphi, qphi, x, M0, S0, ysb);
    hipLaunchKernelGGL(epilogue_kernel, dim3(BB * LL / 4), dim3(128), 0, stream,
                       ysb, WoutT, bout, out);
}

// Round 11
// 2061.989 us; speedup vs baseline: 1.5097x; 1.1648x over previous
//
#include <hip/hip_runtime.h>

#define BB 16
#define LL 512
#define DD 128
#define CH 16
#define NCH (LL / CH)

// 8-lane all-reduce sum (lanes within a DPP half-row), pure VALU:
// quad xor1, quad xor2, then half-row mirror pairs the two quads.
__device__ __forceinline__ float red8(float v) {
    v += __int_as_float(__builtin_amdgcn_update_dpp(
            0, __float_as_int(v), 0xB1, 0xF, 0xF, true));
    v += __int_as_float(__builtin_amdgcn_update_dpp(
            0, __float_as_int(v), 0x4E, 0xF, 0xF, true));
    v += __int_as_float(__builtin_amdgcn_update_dpp(
            0, __float_as_int(v), 0x141, 0xF, 0xF, true));
    return v;
}

#define SCAN_REGS __attribute__((amdgpu_waves_per_eu(2, 2)))

// ---------------- transpose Wq, Wk, Wout (once per call, tiny) ----------------
__global__ void transpose3_kernel(const float* __restrict__ Wq,
                                  const float* __restrict__ Wk,
                                  const float* __restrict__ Wout,
                                  float* __restrict__ WqT,
                                  float* __restrict__ WkT,
                                  float* __restrict__ WoutT) {
    const float* src; float* dst;
    if (blockIdx.x == 0)      { src = Wq;   dst = WqT;   }
    else if (blockIdx.x == 1) { src = Wk;   dst = WkT;   }
    else                      { src = Wout; dst = WoutT; }
    for (int idx = threadIdx.x; idx < DD * DD; idx += blockDim.x) {
        int r = idx >> 7, c = idx & 127;
        dst[c * DD + r] = src[idx];
    }
}

// ---------------- prologue: q/k projections, k-normalize, P0 rotation, poly ----
__global__ __launch_bounds__(128) void prologue_kernel(
        const float* __restrict__ x, const float* __restrict__ WqT,
        const float* __restrict__ WkT, const float* __restrict__ P0,
        const float* __restrict__ log_gain, const float* __restrict__ coeffs,
        float* __restrict__ kphi, float* __restrict__ qphi) {
    const int row0 = blockIdx.x * 4;
    const int e = threadIdx.x;
    __shared__ float xs[4][DD];
    __shared__ float qrow[4][DD];
    __shared__ float wred[4][2];

    #pragma unroll
    for (int rr = 0; rr < 4; ++rr)
        xs[rr][e] = x[(size_t)(row0 + rr) * DD + e];
    __syncthreads();

    float aq[4] = {0,0,0,0}, ak[4] = {0,0,0,0};
    #pragma unroll 4
    for (int d = 0; d < DD; ++d) {
        float wq = WqT[d * DD + e];
        float wk = WkT[d * DD + e];
        #pragma unroll
        for (int rr = 0; rr < 4; ++rr) {
            float xv = xs[rr][d];
            aq[rr] = fmaf(xv, wq, aq[rr]);
            ak[rr] = fmaf(xv, wk, ak[rr]);
        }
    }
    const int lane = threadIdx.x & 63, wv = threadIdx.x >> 6;
    #pragma unroll
    for (int rr = 0; rr < 4; ++rr) {
        float s = ak[rr] * ak[rr];
        #pragma unroll
        for (int m = 1; m <= 32; m <<= 1) s += __shfl_xor(s, m);
        if (lane == 0) wred[rr][wv] = s;
    }
    __syncthreads();
    const float c0 = coeffs[0], c1v = coeffs[1];
    #pragma unroll
    for (int rr = 0; rr < 4; ++rr) {
        float s = wred[rr][0] + wred[rr][1];
        float kn = ak[rr] / fmaxf(sqrtf(s), 1e-12f);
        kphi[(size_t)(row0 + rr) * DD + e] = c0 * kn + c1v * kn * kn;
        qrow[rr][e] = aq[rr];
    }
    __syncthreads();
    float acc[4] = {0,0,0,0};
    #pragma unroll 4
    for (int d = 0; d < DD; ++d) {
        float pv = P0[d * DD + e];
        #pragma unroll
        for (int rr = 0; rr < 4; ++rr) acc[rr] = fmaf(qrow[rr][d], pv, acc[rr]);
    }
    const float g = expf(log_gain[e]);
    #pragma unroll
    for (int rr = 0; rr < 4; ++rr) {
        float qa = tanhf(g * acc[rr]);
        qphi[(size_t)(row0 + rr) * DD + e] = c0 * qa + c1v * qa * qa;
    }
}

// ---------------- main sequential scan: one block per batch --------------------
// Exact R8 structure (champion: chunked LDS staging, vmem-free per-step
// barriers, single accumulators, qq read in phase 6). NEW: a 24 KB dummy LDS
// array pushes static LDS to ~84.5 KB > 160/2 KB, so only ONE block/CU fits at
// compile time -> the scheduler's occupancy target drops to 8 waves/CU
// (2/SIMD) -> register budget 256/wave -> the 128-float state + temps
// (~212 peak live) allocate spill-free. (At 59.9 KB the target was 2 blocks/CU
// = 128 regs, and with state alone = 128 floats every temp spilled to AGPR —
// ~500 copy instr/step, ~45% of issue.) Runtime cost zero: grid=16 on 256 CUs
// is 1 block/CU regardless. R9/R10's liveness-raising "optimizations" reverted.
// Thread (g = tid>>3, j = tid&7): rows {2g,2g+1}; interleaved column set
// col(m,l) = 4j + 32m + l -> conflict-free unpadded vector reads.
// A = S S^T S via exact rank-3 recurrence; ||S||_F^2 via scalar recurrence.
__global__ SCAN_REGS __launch_bounds__(512)
void scan_kernel(
        const float* __restrict__ kphi, const float* __restrict__ qphi,
        const float* __restrict__ x, const float* __restrict__ M0,
        const float* __restrict__ S0, float* __restrict__ ys) {
    const int b    = blockIdx.x;
    const int tid  = threadIdx.x;
    const int j    = tid & 7;
    const int g    = tid >> 3;
    const int r0   = 2 * g;
    const int w    = tid >> 6;
    const int lane = tid & 63;

    __shared__ __align__(16) float kc[2][CH * DD];
    __shared__ __align__(16) float qc[2][CH * DD];
    __shared__ __align__(16) float xc[2][CH * DD];
    __shared__ __align__(16) float yc[CH * DD];
    __shared__ __align__(16) float us[DD], ps[DD], wsv[DD], hs[DD];
    __shared__ float red[64];
    __shared__ float n2sh;
    // occupancy forcer: pushes static LDS > 80 KB so only 1 block/CU fits at
    // compile time (register budget 256/wave). Referenced behind an opaque
    // guard so it is not eliminated; never actually executed (grid = 16).
    __shared__ float ldspad[6144];
    if (b == 0x7FFFFFF) { ldspad[tid] = (float)tid; __syncthreads(); us[0] = ldspad[tid ^ 1]; }

    float S[32], ST[32], A[32], M[32];
    {
        const float4* S04 = (const float4*)S0;
        const float4* M04 = (const float4*)M0;
        #pragma unroll
        for (int rl = 0; rl < 2; ++rl)
            #pragma unroll
            for (int m = 0; m < 4; ++m) {
                int f4 = (r0 + rl) * 32 + j + 8 * m;
                float4 s4 = S04[f4], m4 = M04[f4];
                int i = rl * 16 + 4 * m;
                S[i+0] = s4.x; S[i+1] = s4.y; S[i+2] = s4.z; S[i+3] = s4.w;
                M[i+0] = m4.x; M[i+1] = m4.y; M[i+2] = m4.z; M[i+3] = m4.w;
            }
        #pragma unroll
        for (int rl = 0; rl < 2; ++rl)
            #pragma unroll
            for (int m = 0; m < 4; ++m)
                #pragma unroll
                for (int l = 0; l < 4; ++l)
                    ST[rl*16 + 4*m + l] =
                        S0[(size_t)(4*j + 32*m + l) * DD + r0 + rl];
        #pragma unroll
        for (int i = 0; i < 32; ++i) A[i] = 0.f;   // exact when S0 == 0
    }

    // ||S0||^2 block reduction
    float sp = 0.f;
    #pragma unroll
    for (int i = 0; i < 32; ++i) sp = fmaf(S[i], S[i], sp);
    sp = red8(sp);
    if (j == 0) red[g] = sp;

    const size_t base = (size_t)b * LL * DD;

    // preload chunk 0 (each wave copies 3 x 1KB segments)
    #pragma unroll
    for (int i = 0; i < 3; ++i) {
        int seg = w * 3 + i, arr = seg >> 3, sub = seg & 7;
        const float* sp0 = (arr == 0 ? kphi : (arr == 1 ? qphi : x))
                           + base + sub * 256 + lane * 4;
        float* dp = (arr == 0 ? kc[0] : (arr == 1 ? qc[0] : xc[0]))
                    + sub * 256 + lane * 4;
        *(float4*)dp = *(const float4*)sp0;
    }
    __syncthreads();
    if (tid < 64) {
        float s = red[tid];
        #pragma unroll
        for (int m = 1; m <= 32; m <<= 1) s += __shfl_xor(s, m);
        if (tid == 0) n2sh = s;
    }
    __syncthreads();
    float n2 = n2sh;

    const float a = 0.9f, a2v = 0.81f, a3v = 0.729f;

    #pragma unroll 1
    for (int tc = 0; tc < NCH; ++tc) {
        const int cb = tc & 1;
        const float* kcb = kc[cb];
        const float* qcb = qc[cb];
        const float* xcb = xc[cb];

        #pragma unroll 1
        for (int sl = 0; sl < CH; ++sl) {
            const int so = sl * DD;

            // issue next-chunk staging loads at chunk start (drained ~1x/chunk)
            float4 pre0, pre1, pre2;
            const bool doPre = (sl == 0) && (tc + 1 < NCH);
            if (doPre) {
                const size_t nbg = base + (size_t)(tc + 1) * CH * DD;
                {
                    int seg = w * 3 + 0, arr = seg >> 3, sub = seg & 7;
                    pre0 = *(const float4*)((arr == 0 ? kphi : (arr == 1 ? qphi : x))
                                            + nbg + sub * 256 + lane * 4);
                }
                {
                    int seg = w * 3 + 1, arr = seg >> 3, sub = seg & 7;
                    pre1 = *(const float4*)((arr == 0 ? kphi : (arr == 1 ? qphi : x))
                                            + nbg + sub * 256 + lane * 4);
                }
                {
                    int seg = w * 3 + 2, arr = seg >> 3, sub = seg & 7;
                    pre2 = *(const float4*)((arr == 0 ? kphi : (arr == 1 ? qphi : x))
                                            + nbg + sub * 256 + lane * 4);
                }
            }

            // ---- phase 2 (row side): pred = M k, p = S v, cv = v.v ----
            float kk[16];
            {
                const float4* k4 = (const float4*)(kcb + so);
                #pragma unroll
                for (int m = 0; m < 4; ++m) {
                    float4 v4 = k4[j + 8 * m];
                    kk[4*m+0] = v4.x; kk[4*m+1] = v4.y;
                    kk[4*m+2] = v4.z; kk[4*m+3] = v4.w;
                }
            }
            float pr0 = 0.f, pr1 = 0.f, pp0 = 0.f, pp1 = 0.f, cvp = 0.f;
            #pragma unroll
            for (int cl = 0; cl < 16; ++cl) {
                float kv = kk[cl];
                pr0 = fmaf(M[cl],      kv, pr0);
                pr1 = fmaf(M[16 + cl], kv, pr1);
                pp0 = fmaf(S[cl],      kv, pp0);
                pp1 = fmaf(S[16 + cl], kv, pp1);
                cvp = fmaf(kv, kv, cvp);
            }
            pr0 = red8(pr0); pr1 = red8(pr1);
            pp0 = red8(pp0); pp1 = red8(pp1);
            const float cv = red8(cvp);
            const float2 xv = *(const float2*)&xcb[so + r0];
            const float u0 = pr0 - xv.x, u1 = pr1 - xv.y;
            const float p0 = pp0, p1 = pp1;
            if (j == 0) {
                *(float2*)&us[r0] = make_float2(u0, u1);
                *(float2*)&ps[r0] = make_float2(p0, p1);
            }
            __syncthreads();                               // barrier 1 (LDS only)

            // ---- phase 4 (col side): w = S^T u, h = S^T p, dots; ST update ----
            float uu[16], pa[16];
            {
                const float4* u4 = (const float4*)us;
                const float4* p4 = (const float4*)ps;
                #pragma unroll
                for (int m = 0; m < 4; ++m) {
                    float4 a4 = u4[j + 8 * m], b4 = p4[j + 8 * m];
                    uu[4*m+0] = a4.x; uu[4*m+1] = a4.y;
                    uu[4*m+2] = a4.z; uu[4*m+3] = a4.w;
                    pa[4*m+0] = b4.x; pa[4*m+1] = b4.y;
                    pa[4*m+2] = b4.z; pa[4*m+3] = b4.w;
                }
            }
            const float2 vc = *(const float2*)&kcb[so + r0];
            float w0 = 0.f, w1 = 0.f, h0 = 0.f, h1 = 0.f, cuup = 0.f, cupp = 0.f;
            #pragma unroll
            for (int cl = 0; cl < 16; ++cl) {
                float uv = uu[cl], pv = pa[cl];
                float st0 = ST[cl], st1 = ST[16 + cl];
                w0 = fmaf(st0, uv, w0);  w1 = fmaf(st1, uv, w1);
                h0 = fmaf(st0, pv, h0);  h1 = fmaf(st1, pv, h1);
                cuup = fmaf(uv, uv, cuup);
                cupp = fmaf(uv, pv, cupp);
                ST[cl]      = fmaf(a, st0, vc.x * uv);     // old st used above only
                ST[16 + cl] = fmaf(a, st1, vc.y * uv);
            }
            w0 = red8(w0); w1 = red8(w1); h0 = red8(h0); h1 = red8(h1);
            const float cu  = red8(cuup);
            const float cup = red8(cupp);
            n2 = a2v * n2 + 2.0f * a * cup + cu * cv;      // ||S_t||_F^2 recurrence
            if (j == 0) {
                *(float2*)&wsv[r0] = make_float2(w0, w1);
                *(float2*)&hs[r0]  = make_float2(h0, h1);
            }
            // commit next-chunk staging to the other LDS buffer
            if (doPre) {
                float* kn = kc[cb ^ 1]; float* qn = qc[cb ^ 1]; float* xn = xc[cb ^ 1];
                {
                    int seg = w * 3 + 0, arr = seg >> 3, sub = seg & 7;
                    *(float4*)((arr == 0 ? kn : (arr == 1 ? qn : xn))
                               + sub * 256 + lane * 4) = pre0;
                }
                {
                    int seg = w * 3 + 1, arr = seg >> 3, sub = seg & 7;
                    *(float4*)((arr == 0 ? kn : (arr == 1 ? qn : xn))
                               + sub * 256 + lane * 4) = pre1;
                }
                {
                    int seg = w * 3 + 2, arr = seg >> 3, sub = seg & 7;
                    *(float4*)((arr == 0 ? kn : (arr == 1 ? qn : xn))
                               + sub * 256 + lane * 4) = pre2;
                }
            }
            __syncthreads();                               // barrier 2 (LDS only*)

            // ---- phase 6 (row side): g = S w; rank-3 A; S, M updates; y = M q ----
            float ww[16], hh[16], qq[16];
            {
                const float4* w4 = (const float4*)wsv;
                const float4* h4 = (const float4*)hs;
                const float4* q4 = (const float4*)(qcb + so);
                #pragma unroll
                for (int m = 0; m < 4; ++m) {
                    float4 a4 = w4[j + 8 * m], b4 = h4[j + 8 * m], c4v = q4[j + 8 * m];
                    ww[4*m+0] = a4.x;  ww[4*m+1] = a4.y;
                    ww[4*m+2] = a4.z;  ww[4*m+3] = a4.w;
                    hh[4*m+0] = b4.x;  hh[4*m+1] = b4.y;
                    hh[4*m+2] = b4.z;  hh[4*m+3] = b4.w;
                    qq[4*m+0] = c4v.x; qq[4*m+1] = c4v.y;
                    qq[4*m+2] = c4v.z; qq[4*m+3] = c4v.w;
                }
            }
            float g0 = 0.f, g1 = 0.f;
            #pragma unroll
            for (int cl = 0; cl < 16; ++cl) {
                g0 = fmaf(S[cl],      ww[cl], g0);
                g1 = fmaf(S[16 + cl], ww[cl], g1);
            }
            g0 = red8(g0); g1 = red8(g1);

            const float rho0 = a2v * g0 + a * cu * p0 + (a * cup + cv * cu) * u0;
            const float rho1 = a2v * g1 + a * cu * p1 + (a * cup + cv * cu) * u1;
            const float sg0  = a2v * p0 + a * cv * u0;
            const float sg1  = a2v * p1 + a * cv * u1;
            const float ta0  = a2v * u0, ta1 = a2v * u1;
            const float nrm  = sqrtf(fmaxf(n2, 0.f)) + 1e-6f;
            const float rn   = 1.0f / nrm;
            const float c1   = -0.015f * rn;    // 0.99M - 0.01*(1.5 S/n - 0.5 A/n^3)
            const float c2   = 0.005f * rn * rn * rn;

            float y0 = 0.f, y1 = 0.f;
            #pragma unroll
            for (int cl = 0; cl < 16; ++cl) {
                float kv = kk[cl], wv = ww[cl], hv = hh[cl], qv = qq[cl];
                S[cl]      = fmaf(a, S[cl],      u0 * kv);
                S[16 + cl] = fmaf(a, S[16 + cl], u1 * kv);
                A[cl]      = fmaf(a3v, A[cl],
                                  fmaf(rho0, kv, fmaf(sg0, wv, ta0 * hv)));
                A[16 + cl] = fmaf(a3v, A[16 + cl],
                                  fmaf(rho1, kv, fmaf(sg1, wv, ta1 * hv)));
                M[cl]      = fmaf(0.99f, M[cl],      fmaf(c1, S[cl],      c2 * A[cl]));
                M[16 + cl] = fmaf(0.99f, M[16 + cl], fmaf(c1, S[16 + cl], c2 * A[16 + cl]));
                y0 = fmaf(M[cl],      qv, y0);
                y1 = fmaf(M[16 + cl], qv, y1);
            }
            y0 = red8(y0); y1 = red8(y1);
            if (j == 0)
                *(float2*)&yc[so + r0] = make_float2(y0, y1);
        }

        // chunk end: flush yc -> ys (one float4 per thread)
        __syncthreads();
        float4 yv = *(float4*)&yc[tid * 4];
        *(float4*)(ys + base + (size_t)tc * CH * DD + tid * 4) = yv;
    }
}

// ---------------- epilogue: out = ys @ Wout^T + bout ---------------------------
__global__ __launch_bounds__(128) void epilogue_kernel(
        const float* __restrict__ ys, const float* __restrict__ WoutT,
        const float* __restrict__ bout, float* __restrict__ out) {
    const int row0 = blockIdx.x * 4;
    const int e = threadIdx.x;
    __shared__ float yr[4][DD];
    #pragma unroll
    for (int rr = 0; rr < 4; ++rr)
        yr[rr][e] = ys[(size_t)(row0 + rr) * DD + e];
    __syncthreads();
    float acc[4] = {0,0,0,0};
    #pragma unroll 4
    for (int d = 0; d < DD; ++d) {
        float w = WoutT[d * DD + e];
        #pragma unroll
        for (int rr = 0; rr < 4; ++rr) acc[rr] = fmaf(yr[rr][d], w, acc[rr]);
    }
    const float bo = bout[e];
    #pragma unroll
    for (int rr = 0; rr < 4; ++rr)
        out[(size_t)(row0 + rr) * DD + e] = acc[rr] + bo;
}

extern "C" void kernel_launch(void* const* d_in, const int* in_sizes, int n_in,
                              void* d_out, int out_size, void* d_ws, size_t ws_size,
                              hipStream_t stream) {
    const float* x        = (const float*)d_in[0];
    const float* Wq       = (const float*)d_in[1];
    const float* Wk       = (const float*)d_in[2];
    const float* P0       = (const float*)d_in[3];
    const float* M0       = (const float*)d_in[4];
    const float* S0       = (const float*)d_in[5];
    const float* log_gain = (const float*)d_in[6];
    const float* coeffs   = (const float*)d_in[7];
    const float* Wout     = (const float*)d_in[8];
    const float* bout     = (const float*)d_in[9];
    float* out = (float*)d_out;

    float* ws    = (float*)d_ws;
    float* WqT   = ws;                      // 16384
    float* WkT   = ws + 16384;              // 16384
    float* WoutT = ws + 32768;              // 16384
    float* kphi  = ws + 49152;              // B*L*D each below
    float* qphi  = kphi + (size_t)BB * LL * DD;
    float* ysb   = qphi + (size_t)BB * LL * DD;

    hipLaunchKernelGGL(transpose3_kernel, dim3(3), dim3(256), 0, stream,
                       Wq, Wk, Wout, WqT, WkT, WoutT);
    hipLaunchKernelGGL(prologue_kernel, dim3(BB * LL / 4), dim3(128), 0, stream,
                       x, WqT, WkT, P0, log_gain, coeffs, kphi, qphi);
    hipLaunchKernelGGL(scan_kernel, dim3(BB), dim3(512), 0, stream,
                       kphi, qphi, x, M0, S0, ysb);
    hipLaunchKernelGGL(epilogue_kernel, dim3(BB * LL / 4), dim3(128), 0, stream,
                       ysb, WoutT, bout, out);
}